// Round 7
// baseline (293.469 us; speedup 1.0000x reference)
//
#include <hip/hip_runtime.h>

#define D_DIM 2048
#define E_DIM 64
#define BT 128                   // tokens per block
#define DSPLIT 4
#define DCH (D_DIM / DSPLIT)     // 512
#define DK 16                    // depth per x LDS tile (16 floats = 4 chunks)
#define NTILE (DCH / DK)         // 32
#define XB (BT * DK * 4)         // 8192 B per ring buffer
#define NBUF 4                   // 32 KB LDS total

typedef __attribute__((address_space(3))) char as3_char;
typedef __attribute__((address_space(1))) const char as1_char;

// Block (bx,by): tokens [bx*128,+128) x all 64 experts over D-chunk
// [by*512,+512). W lives in VGPRs (reloaded per 8-d half-tile from L2,
// broadcast-merged across lanes); LDS carries only x (0.5 B/FMA -> FMA-bound,
// vs 1.5 B/FMA in the all-LDS design that stalled at 35% VALUBusy).
__global__ __launch_bounds__(256, 2) void router_gemm(
    const float* __restrict__ x, const float* __restrict__ w,
    float* __restrict__ out, int N) {
  __shared__ __align__(16) char lds[NBUF][XB];
  const int tid = threadIdx.x;
  const int l = tid & 63;
  const int wv = tid >> 6;
  const int tbase = blockIdx.x * BT;
  const int dbase = blockIdx.y * DCH;

  // ---- x staging: linear LDS dest; source pre-swizzled so stored chunk s of
  // row r holds global chunk s ^ ((r>>1)&3) (rows are 64 B = 4 chunks).
  const int scol = ((l & 3) ^ ((l >> 3) & 3)) * 4;  // floats
  const float* xsrc[2];
#pragma unroll
  for (int q = 0; q < 2; ++q) {
    int row = (wv * 2 + q) * 16 + (l >> 2);  // 8 groups cover 128 rows
    xsrc[q] = x + (size_t)(tbase + row) * D_DIM + dbase + scol;
  }

  auto STAGE = [&](int b, int t) {
    const int d0 = t * DK;
#pragma unroll
    for (int q = 0; q < 2; ++q)
      __builtin_amdgcn_global_load_lds(
          (as1_char*)(const char*)(xsrc[q] + d0),
          (as3_char*)&lds[b][(wv * 2 + q) * 1024], 16, 0, 0);
  };

  // ---- compute mapping: thread (tg,eg) owns tokens {tg+32i, i<4} x experts
  // {eg*8+j, j<8}. Read addr = base ^ (chunk<<4) (swizzle bits = byte 4-5).
  const int tg = tid & 31;
  const int eg = tid >> 5;
  int xoff[4];
#pragma unroll
  for (int i = 0; i < 4; ++i)
    xoff[i] = (tg + 32 * i) * 64 + (((tg >> 1) & 3) << 4);

  const float* wp[8];
#pragma unroll
  for (int j = 0; j < 8; ++j)
    wp[j] = w + (size_t)(eg * 8 + j) * D_DIM + dbase;

  float acc[4][8];
#pragma unroll
  for (int i = 0; i < 4; ++i)
#pragma unroll
    for (int j = 0; j < 8; ++j) acc[i][j] = 0.f;

  float4 wAv[8][2], wBv[8][2];  // W for half-A (d 0-7) / half-B (d 8-15)

  // prologue: 3-deep x ring + W for tile 0 half-A
  STAGE(0, 0);
  STAGE(1, 1);
  STAGE(2, 2);
#pragma unroll
  for (int j = 0; j < 8; ++j)
#pragma unroll
    for (int p = 0; p < 2; ++p)
      wAv[j][p] = *(const float4*)(wp[j] + p * 4);

  for (int t = 0; t < NTILE; ++t) {
    // wA(t)'s 16 loads are the newest outstanding VMEM ops at this point;
    // vmcnt(16) forces everything older -- i.e. all x-stages through t+2 --
    // to complete, so stage(t) is ready. wA itself is waited by the
    // compiler's dependence-driven waitcnt before first use.
    asm volatile("s_waitcnt vmcnt(16)" ::: "memory");
    __builtin_amdgcn_s_barrier();        // raw barrier: no implicit drain
    __builtin_amdgcn_sched_barrier(0);   // pin issue points below barrier

    // issue W half-B(t) then stage(t+3) (order matters for vmcnt logic)
#pragma unroll
    for (int j = 0; j < 8; ++j)
#pragma unroll
      for (int p = 0; p < 2; ++p)
        wBv[j][p] = *(const float4*)(wp[j] + t * DK + 8 + p * 4);
    if (t + 3 < NTILE) STAGE((t + 3) & 3, t + 3);

    const char* buf = lds[t & 3];

    // half-A: chunks 0,1 with wAv
#pragma unroll
    for (int c = 0; c < 2; ++c) {
      float4 xv[4];
#pragma unroll
      for (int i = 0; i < 4; ++i)
        xv[i] = *(const float4*)(buf + (xoff[i] ^ (c << 4)));
#pragma unroll
      for (int i = 0; i < 4; ++i)
#pragma unroll
        for (int j = 0; j < 8; ++j) {
          acc[i][j] = fmaf(xv[i].x, wAv[j][c].x, acc[i][j]);
          acc[i][j] = fmaf(xv[i].y, wAv[j][c].y, acc[i][j]);
          acc[i][j] = fmaf(xv[i].z, wAv[j][c].z, acc[i][j]);
          acc[i][j] = fmaf(xv[i].w, wAv[j][c].w, acc[i][j]);
        }
    }

    // issue W half-A(t+1) (WAR on wAv keeps it after half-A's FMAs)
    if (t + 1 < NTILE) {
#pragma unroll
      for (int j = 0; j < 8; ++j)
#pragma unroll
        for (int p = 0; p < 2; ++p)
          wAv[j][p] = *(const float4*)(wp[j] + (t + 1) * DK + p * 4);
    }

    // half-B: chunks 2,3 with wBv
#pragma unroll
    for (int c = 0; c < 2; ++c) {
      float4 xv[4];
#pragma unroll
      for (int i = 0; i < 4; ++i)
        xv[i] = *(const float4*)(buf + (xoff[i] ^ ((c + 2) << 4)));
#pragma unroll
      for (int i = 0; i < 4; ++i)
#pragma unroll
        for (int j = 0; j < 8; ++j) {
          acc[i][j] = fmaf(xv[i].x, wBv[j][c].x, acc[i][j]);
          acc[i][j] = fmaf(xv[i].y, wBv[j][c].y, acc[i][j]);
          acc[i][j] = fmaf(xv[i].z, wBv[j][c].z, acc[i][j]);
          acc[i][j] = fmaf(xv[i].w, wBv[j][c].w, acc[i][j]);
        }
    }
  }

  // partial store: region = blockIdx.y, contiguous experts -> 2 float4/row
  float* part = out + (size_t)blockIdx.y * ((size_t)N * E_DIM);
#pragma unroll
  for (int i = 0; i < 4; ++i) {
    size_t o = (size_t)(tbase + tg + 32 * i) * E_DIM + eg * 8;
    *(float4*)(part + o) = make_float4(acc[i][0], acc[i][1], acc[i][2], acc[i][3]);
    *(float4*)(part + o + 4) = make_float4(acc[i][4], acc[i][5], acc[i][6], acc[i][7]);
  }
}

__global__ __launch_bounds__(256) void postprocess(float* out, float* ws, int N) {
  const int lane = threadIdx.x & 63;
  const int wv = threadIdx.x >> 6;
  const size_t NE = (size_t)N * E_DIM;
  float* disp = out;               // holds partial 0 on entry
  float* comb = out + NE;          // partial 1
  float* logits_o = out + 2 * NE;  // partial 2
  float* probs_o = out + 3 * NE;   // partial 3
  float* idx_o = out + 4 * NE + 1;
  float* pn_o = out + 4 * NE + 1 + 2 * (size_t)N;

  float expsum = 0.f;  // per-lane (= per-expert) prob sum over this wave's tokens
  const int t0 = blockIdx.x * 64 + wv * 16;
  for (int k = 0; k < 16; ++k) {
    const size_t t = (size_t)(t0 + k);
    const size_t o = t * E_DIM + lane;
    float lv = (disp[o] + comb[o]) + (logits_o[o] + probs_o[o]);
    logits_o[o] = lv;  // all 4 partials for this token already read
    float m = lv;
#pragma unroll
    for (int off = 32; off; off >>= 1) m = fmaxf(m, __shfl_xor(m, off));
    float p = __expf(lv - m);
    float s = p;
#pragma unroll
    for (int off = 32; off; off >>= 1) s += __shfl_xor(s, off);
    float prob = p / s;
    probs_o[o] = prob;
    expsum += prob;

    // packed key: prob bits | (63-lane) -> lowest index wins ties (jax top_k)
    unsigned long long key =
        ((unsigned long long)__float_as_uint(prob) << 32) | (unsigned)(63 - lane);
    unsigned long long k1 = key;
#pragma unroll
    for (int off = 32; off; off >>= 1) {
      unsigned long long v = __shfl_xor(k1, off);
      if (v > k1) k1 = v;
    }
    int i1 = 63 - (int)(k1 & 63);
    unsigned long long k2 = (lane == i1) ? 0ull : key;
#pragma unroll
    for (int off = 32; off; off >>= 1) {
      unsigned long long v = __shfl_xor(k2, off);
      if (v > k2) k2 = v;
    }
    int i2 = 63 - (int)(k2 & 63);
    float p1 = __uint_as_float((unsigned)(k1 >> 32));
    float p2 = __uint_as_float((unsigned)(k2 >> 32));
    float inv = 1.0f / (p1 + p2);
    float pn1 = p1 * inv, pn2 = p2 * inv;
    float dval = (lane == i1) ? pn1 : ((lane == i2) ? pn2 : 0.f);
    disp[o] = dval;
    comb[o] = dval;
    if (lane == 0) {
      idx_o[2 * t] = (float)i1;
      idx_o[2 * t + 1] = (float)i2;
      pn_o[2 * t] = pn1;
      pn_o[2 * t + 1] = pn2;
    }
  }

  __shared__ float aux_s[4][64];
  aux_s[wv][lane] = expsum;
  __syncthreads();
  if (threadIdx.x < 64) {
    float s = aux_s[0][threadIdx.x] + aux_s[1][threadIdx.x] +
              aux_s[2][threadIdx.x] + aux_s[3][threadIdx.x];
    ws[(size_t)blockIdx.x * 64 + threadIdx.x] = s;  // per-block expert partials
  }
}

__global__ __launch_bounds__(256) void finalize_aux(const float* __restrict__ ws,
                                                    float* __restrict__ auxp,
                                                    int nblocks, int N) {
  __shared__ float red[256];
  const int e = threadIdx.x & 63;
  const int part = threadIdx.x >> 6;
  float s = 0.f;
  for (int b = part; b < nblocks; b += 4) s += ws[(size_t)b * 64 + e];
  red[threadIdx.x] = s;
  __syncthreads();
  if (threadIdx.x < 64) {
    float tot = red[e] + red[64 + e] + red[128 + e] + red[192 + e];
    float pb = tot / (float)N;
    float v = pb * pb;  // aux = mean_e(E*pb^2) = sum_e pb^2
#pragma unroll
    for (int off = 32; off; off >>= 1) v += __shfl_xor(v, off);
    if (threadIdx.x == 0) *auxp = v;
  }
}

extern "C" void kernel_launch(void* const* d_in, const int* in_sizes, int n_in,
                              void* d_out, int out_size, void* d_ws, size_t ws_size,
                              hipStream_t stream) {
  (void)n_in; (void)out_size; (void)ws_size;
  const float* x = (const float*)d_in[0];
  const float* w = (const float*)d_in[1];
  float* out = (float*)d_out;
  const int N = in_sizes[0] / D_DIM;  // 16384
  const int npb = N / 64;             // postprocess blocks (256)

  dim3 gg(N / BT, DSPLIT);  // 128 x 4 = 512 blocks (2 per CU)
  router_gemm<<<gg, dim3(256), 0, stream>>>(x, w, out, N);
  postprocess<<<dim3(npb), dim3(256), 0, stream>>>(out, (float*)d_ws, N);
  finalize_aux<<<dim3(1), dim3(256), 0, stream>>>((const float*)d_ws,
                                                  out + 4 * (size_t)N * E_DIM,
                                                  npb, N);
}